// Round 12
// baseline (409.563 us; speedup 1.0000x reference)
//
#include <hip/hip_runtime.h>
#include <hip/hip_bf16.h>

#define EPS_LN 1e-5f

typedef __attribute__((ext_vector_type(8))) short bf16x8;
typedef __attribute__((ext_vector_type(4))) float f32x4;

__device__ __forceinline__ float dot4(float4 a, float4 b) {
    return a.x * b.x + a.y * b.y + a.z * b.z + a.w * b.w;
}
__device__ __forceinline__ float sigmoidf_(float x) { return 1.0f / (1.0f + expf(-x)); }

__device__ __forceinline__ float bfu2f(unsigned short u) {
    unsigned v = ((unsigned)u) << 16;
    float f;
    __builtin_memcpy(&f, &v, 4);
    return f;
}
__device__ __forceinline__ unsigned short f2bfu(float f) {
    __hip_bfloat16 h = __float2bfloat16(f);
    unsigned short u;
    __builtin_memcpy(&u, &h, 2);
    return u;
}
__device__ __forceinline__ unsigned pack2bf(float a, float b) {
    return (unsigned)f2bfu(a) | ((unsigned)f2bfu(b) << 16);
}
// async global->LDS 16B copy (vmcnt-tracked; __syncthreads drains)
__device__ __forceinline__ void async_cp16(void* lds, const void* g) {
    __builtin_amdgcn_global_load_lds((const __attribute__((address_space(1))) void*)g,
                                     (__attribute__((address_space(3))) void*)lds, 16, 0, 0);
}

// ---------------- lin0 + degree counts fused ----------------
__global__ void init_kernel(const float* __restrict__ x, const float* __restrict__ w,
                            const float* __restrict__ b, float* __restrict__ h,
                            const int* __restrict__ ei, float* __restrict__ counts,
                            int N, int E) {
    int id = blockIdx.x * blockDim.x + threadIdx.x;
    if (id < N * 64) {
        int n = id >> 6, o = id & 63;
        const float* xr = x + n * 16;
        const float* wr = w + o * 16;
        float acc = b[o];
#pragma unroll
        for (int k = 0; k < 16; k++) acc += xr[k] * wr[k];
        h[id] = fmaxf(acc, 0.0f);
    }
    if (id < E) atomicAdd(&counts[ei[E + id]], 1.0f);
}

// ---------------- edge NN layer 1 -> e1 hi/lo bf16, PRE-SWIZZLED storage ----------------
__global__ __launch_bounds__(128) void edge_nn1_kernel(
    const float* __restrict__ ea, const float* __restrict__ w1, const float* __restrict__ b1,
    const float* __restrict__ g1, const float* __restrict__ b1n,
    unsigned short* __restrict__ e1h, unsigned short* __restrict__ e1l, int E) {
    int e = blockIdx.x, j = threadIdx.x;
    float a0 = ea[e * 4 + 0], a1 = ea[e * 4 + 1], a2 = ea[e * 4 + 2], a3 = ea[e * 4 + 3];
    const float* wr = w1 + j * 4;
    float z = b1[j] + a0 * wr[0] + a1 * wr[1] + a2 * wr[2] + a3 * wr[3];
    float s = z, s2 = z * z;
#pragma unroll
    for (int m = 32; m >= 1; m >>= 1) { s += __shfl_xor(s, m); s2 += __shfl_xor(s2, m); }
    __shared__ float ls[2], ls2[2];
    int wv = j >> 6;
    if ((j & 63) == 0) { ls[wv] = s; ls2[wv] = s2; }
    __syncthreads();
    float S = ls[0] + ls[1], S2 = ls2[0] + ls2[1];
    float mu = S * (1.0f / 128.0f);
    float var = fmaxf(S2 * (1.0f / 128.0f) - mu * mu, 0.0f);
    float inv = rsqrtf(var + EPS_LN);
    float v = fmaxf((z - mu) * inv * g1[j] + b1n[j], 0.0f);
    unsigned short hi = f2bfu(v);
    unsigned short lo = f2bfu(v - bfu2f(hi));
    int jp = j ^ ((e & 7) << 3);
    e1h[e * 128 + jp] = hi;
    e1l[e * 128 + jp] = lo;
}

// ---------------- M partials + W2 fold into w2gp (chunk-permuted + swizzled) ----------------
__global__ __launch_bounds__(128) void mpart_kernel(const float* __restrict__ w2,
                                                    const float* __restrict__ b2,
                                                    const float* __restrict__ g2,
                                                    unsigned short* __restrict__ w2gp,
                                                    float* __restrict__ b2g,
                                                    float* __restrict__ pMT, float* __restrict__ pv,
                                                    float* __restrict__ pcw, float* __restrict__ psb,
                                                    float* __restrict__ pc) {
    __shared__ float wL[16][128];
    __shared__ float b2L[16];
    int t = threadIdx.x, b = blockIdx.x;
#pragma unroll
    for (int i = 0; i < 16; i++) {
        int idx = t + i * 128;
        wL[idx >> 7][idx & 127] = w2[(size_t)(b * 16 + (idx >> 7)) * 128 + (idx & 127)];
    }
    if (t < 16) b2L[t] = b2[b * 16 + t];
    __syncthreads();
#pragma unroll
    for (int o = 0; o < 16; o++) {
        int r = b * 16 + o;
        int x = (r & 63) >> 1;
        int jj = (r >> 6) + ((r & 1) << 6);
        w2gp[(size_t)x * 16384 + jj * 128 + (t ^ ((jj & 7) << 3))] = f2bfu(wL[o][t] * g2[r]);
    }
    if (t < 16) b2g[b * 16 + t] = b2L[t] * g2[b * 16 + t];
    int j = t;
    float wj[16];
#pragma unroll
    for (int o = 0; o < 16; o++) wj[o] = wL[o][j];
    float pvj = 0.f, pcwj = 0.f;
#pragma unroll
    for (int o = 0; o < 16; o++) { pvj += wj[o] * b2L[o]; pcwj += wj[o]; }
    for (int i4 = 0; i4 < 32; i4++) {
        float4 a = {0.f, 0.f, 0.f, 0.f};
#pragma unroll
        for (int o = 0; o < 16; o++) {
            float4 w4 = *(const float4*)&wL[o][i4 * 4];
            a.x += wj[o] * w4.x; a.y += wj[o] * w4.y;
            a.z += wj[o] * w4.z; a.w += wj[o] * w4.w;
        }
        *(float4*)&pMT[((size_t)b * 128 + j) * 128 + i4 * 4] = a;
    }
    pv[b * 128 + j] = pvj;
    pcw[b * 128 + j] = pcwj;
    if (t == 0) {
        float sb = 0.f, cc = 0.f;
#pragma unroll
        for (int o = 0; o < 16; o++) { sb += b2L[o]; cc += b2L[o] * b2L[o]; }
        psb[b] = sb;
        pc[b] = cc;
    }
}

// ---------------- reduce partials -> Mb (bf16), varr, cw, sbc ----------------
__global__ __launch_bounds__(256) void mreduce_kernel(const float* __restrict__ pMT,
                                                      const float* __restrict__ pv,
                                                      const float* __restrict__ pcw,
                                                      const float* __restrict__ psb,
                                                      const float* __restrict__ pc,
                                                      unsigned short* __restrict__ mb,
                                                      float* __restrict__ varr,
                                                      float* __restrict__ cw,
                                                      float* __restrict__ sbc) {
    int fid = blockIdx.x * 256 + threadIdx.x;  // < 16384
    float s = 0.f;
    int j = fid >> 7, i = fid & 127;
    for (int b = 0; b < 256; b++) s += pMT[((size_t)b * 128 + j) * 128 + i];
    mb[fid] = f2bfu(s);
    if (fid < 128) {
        float sv = 0.f, sc = 0.f;
        for (int b = 0; b < 256; b++) { sv += pv[b * 128 + fid]; sc += pcw[b * 128 + fid]; }
        varr[fid] = sv;
        cw[fid] = sc;
    }
    if (fid == 0) {
        float sb = 0.f, cc = 0.f;
        for (int b = 0; b < 256; b++) { sb += psb[b]; cc += pc[b]; }
        sbc[0] = sb;
        sbc[1] = cc;
    }
}

// ---------------- per-edge LN stats via quadratic form, MFMA ----------------
__global__ __launch_bounds__(256) void stats_kernel(
    const unsigned short* __restrict__ e1h, const unsigned short* __restrict__ e1l,
    const unsigned short* __restrict__ mb, const float* __restrict__ cw,
    const float* __restrict__ varr, const float* __restrict__ sbc,
    float* __restrict__ stats, int E) {
    __shared__ __align__(16) unsigned char smem[65536];
    const int t = threadIdx.x;
    const int eb = blockIdx.x * 64;
#pragma unroll
    for (int r = 0; r < 4; r++) {
        int idx = t + r * 256;
        int row = idx >> 4, kseg = idx & 15;
        int er = eb + row;
        if (er >= E) er = E - 1;
        uint4 vh = *(const uint4*)&e1h[(size_t)er * 128 + kseg * 8];
        uint4 vl = *(const uint4*)&e1l[(size_t)er * 128 + kseg * 8];
        int off = row * 256 + kseg * 16;  // linear: source is pre-swizzled
        *(uint4*)(smem + off) = vh;
        *(uint4*)(smem + 16384 + off) = vl;
    }
#pragma unroll
    for (int r = 0; r < 8; r++) {
        int idx = t + r * 256;
        int row = idx >> 4, kseg = idx & 15;
        uint4 v = *(const uint4*)&mb[(size_t)row * 128 + kseg * 8];
        *(uint4*)(smem + 32768 + row * 256 + ((kseg * 16) ^ ((row & 7) << 4))) = v;
    }
    __syncthreads();
    const int w = t >> 6, lane = t & 63;
    const int wrow = w * 16;
    const int r16 = lane & 15, kg = lane >> 4;
    f32x4 tacc[8];
#pragma unroll
    for (int nj = 0; nj < 8; nj++) tacc[nj] = (f32x4){0.f, 0.f, 0.f, 0.f};
#pragma unroll
    for (int ks = 0; ks < 4; ks++) {
        int arow = wrow + r16;
        int koff = ks * 64 + kg * 16;
        bf16x8 ah = *(const bf16x8*)(smem + arow * 256 + (koff ^ ((arow & 7) << 4)));
        bf16x8 al = *(const bf16x8*)(smem + 16384 + arow * 256 + (koff ^ ((arow & 7) << 4)));
#pragma unroll
        for (int nj = 0; nj < 8; nj++) {
            int brow = nj * 16 + r16;
            bf16x8 bf = *(const bf16x8*)(smem + 32768 + brow * 256 + (koff ^ ((brow & 7) << 4)));
            tacc[nj] = __builtin_amdgcn_mfma_f32_16x16x32_bf16(ah, bf, tacc[nj], 0, 0, 0);
            tacc[nj] = __builtin_amdgcn_mfma_f32_16x16x32_bf16(al, bf, tacc[nj], 0, 0, 0);
        }
    }
    __syncthreads();
#pragma unroll
    for (int nj = 0; nj < 8; nj++)
#pragma unroll
        for (int r = 0; r < 4; r++) {
            int row = wrow + kg * 4 + r, col = nj * 16 + r16;
            *(float*)(smem + 32768 + row * 512 + col * 4) = tacc[nj][r];
        }
    __syncthreads();
    int el = t >> 2, q = t & 3;
    float s2p = 0.f, sp = 0.f, svp = 0.f;
    for (int kk = 0; kk < 32; kk++) {
        int k = q * 32 + kk;
        int boff = el * 256 + ((2 * k) ^ ((el & 7) << 4));
        float e1v = bfu2f(*(const unsigned short*)(smem + boff)) +
                    bfu2f(*(const unsigned short*)(smem + 16384 + boff));
        float tv = *(const float*)(smem + 32768 + el * 512 + k * 4);
        s2p += tv * e1v;
        sp += e1v * cw[k];
        svp += e1v * varr[k];
    }
    s2p += __shfl_xor(s2p, 1); s2p += __shfl_xor(s2p, 2);
    sp += __shfl_xor(sp, 1);   sp += __shfl_xor(sp, 2);
    svp += __shfl_xor(svp, 1); svp += __shfl_xor(svp, 2);
    if (q == 0) {
        int e = eb + el;
        if (e < E) {
            float S = sp + sbc[0];
            float S2 = s2p + 2.f * svp + sbc[1];
            float mu = S * (1.0f / 4096.0f);
            float var = fmaxf(S2 * (1.0f / 4096.0f) - mu * mu, 0.0f);
            float inv = rsqrtf(var + EPS_LN);
            stats[e * 2 + 0] = inv;
            stats[e * 2 + 1] = mu * inv;
        }
    }
}

// ---------------- z-GEMM + LN fold + FUSED msg iteration 1 (layout UNCHANGED) ----
// Stores identical to round-11 (zT[e][o*64+d], ushort4). Fusion adds: early-issued
// h1[src] float4 loads (hidden under MFMA), pm=EW.h1 per (edge,o), kg-shfl reduce,
// one atomic per (edge,o) into agg0. Saves one full msg pass.
__global__ __launch_bounds__(256) void zgemm_final(
    const unsigned short* __restrict__ e1h,
    const unsigned short* __restrict__ w2gp, const float* __restrict__ b2g,
    const float* __restrict__ g2, const float* __restrict__ b2n,
    const float* __restrict__ stats, const float* __restrict__ h1,
    const int* __restrict__ ei, float* __restrict__ agg0,
    unsigned short* __restrict__ zT, int E) {
    __shared__ __align__(16) unsigned char smem[49152];  // A [0,16K) + B [16K,48K)
    __shared__ float cBg[128], cGg[128], cBn[128];
    __shared__ float sInv[64], sMiv[64];
    __shared__ int sSrc[64], sDst[64];
    const int t = threadIdx.x;
    const int w = t >> 6, lane = t & 63;
    const int eb = blockIdx.y * 64;
    const int cb = blockIdx.x * 128;
    const int o0 = blockIdx.x * 2;
    // ---- async staging ----
    {
        const char* srcA = (const char*)e1h + (size_t)eb * 256 + w * 1024 + lane * 16;
        char* dstA = (char*)smem + w * 1024 + lane * 16;
#pragma unroll
        for (int i = 0; i < 4; i++) async_cp16(dstA + i * 4096, srcA + i * 4096);
        const char* srcB = (const char*)w2gp + (size_t)blockIdx.x * 32768 + w * 1024 + lane * 16;
        char* dstB = (char*)smem + 16384 + w * 1024 + lane * 16;
#pragma unroll
        for (int i = 0; i < 8; i++) async_cp16(dstB + i * 4096, srcB + i * 4096);
    }
    // ---- per-col LN consts + per-edge stats/src/dst into LDS ----
    if (t < 128) {
        int sj = ((t & 63) << 6) + o0 + (t >> 6);
        cBg[t] = b2g[sj];
        cGg[t] = g2[sj];
        cBn[t] = b2n[sj];
    } else if (t < 192) {
        int tt = t - 128;
        int eg = eb + tt;
        if (eg >= E) eg = E - 1;
        sInv[tt] = stats[eg * 2 + 0];
        sMiv[tt] = stats[eg * 2 + 1];
    } else {
        int tt = t - 192;
        int eg = eb + tt;
        if (eg >= E) eg = E - 1;
        sSrc[tt] = ei[eg];
        sDst[tt] = ei[E + eg];
    }
    __syncthreads();  // drains vmcnt -> LDS tiles ready
    const int wrow = (w >> 1) * 32, wcol = (w & 1) * 64;
    const int og = o0 + (w & 1);
    const int r16 = lane & 15, kg = lane >> 4;

    // ---- EARLY-ISSUE h1 gathers (consumed only in epilogue; latency hidden by MFMA) ----
    float4 h4[2][4];
#pragma unroll
    for (int mi = 0; mi < 2; mi++) {
        int src = sSrc[wrow + mi * 16 + r16];
#pragma unroll
        for (int nj = 0; nj < 4; nj++) {
            int d0 = nj * 16 + kg * 4;
            h4[mi][nj] = *(const float4*)&h1[(size_t)src * 64 + d0];
        }
    }

    f32x4 acc[2][4];
#pragma unroll
    for (int mi = 0; mi < 2; mi++)
#pragma unroll
        for (int nj = 0; nj < 4; nj++) acc[mi][nj] = (f32x4){0.f, 0.f, 0.f, 0.f};
#pragma unroll
    for (int ks = 0; ks < 4; ks++) {
        int koff = ks * 64 + kg * 16;
        bf16x8 af[2];
#pragma unroll
        for (int mi = 0; mi < 2; mi++) {
            int row = wrow + mi * 16 + r16;
            af[mi] = *(const bf16x8*)(smem + row * 256 + (koff ^ ((row & 7) << 4)));
        }
        bf16x8 bf[4];
#pragma unroll
        for (int nj = 0; nj < 4; nj++) {
            int row = wcol + nj * 16 + r16;
            bf[nj] = *(const bf16x8*)(smem + 16384 + row * 256 + (koff ^ ((row & 7) << 4)));
        }
#pragma unroll
        for (int mi = 0; mi < 2; mi++)
#pragma unroll
            for (int nj = 0; nj < 4; nj++)
                acc[mi][nj] = __builtin_amdgcn_mfma_f32_16x16x32_bf16(
                    bf[nj], af[mi], acc[mi][nj], 0, 0, 0);  // SWAPPED: D' = (A.B^T)^T
    }
    // ---- epilogue: stores (unchanged) + fused msg1 partial ----
#pragma unroll
    for (int mi = 0; mi < 2; mi++) {
        int e_local = wrow + mi * 16 + r16;
        int e = eb + e_local;
        float inv = sInv[e_local], miv = sMiv[e_local];
        bool ok = (e < E);
        float pm = 0.f;
#pragma unroll
        for (int nj = 0; nj < 4; nj++) {
            int j0 = wcol + nj * 16 + kg * 4;
            float4 bg4 = *(const float4*)&cBg[j0];
            float4 gg4 = *(const float4*)&cGg[j0];
            float4 bn4 = *(const float4*)&cBn[j0];
            float v0 = inv * (acc[mi][nj][0] + bg4.x) - miv * gg4.x + bn4.x;
            float v1 = inv * (acc[mi][nj][1] + bg4.y) - miv * gg4.y + bn4.y;
            float v2 = inv * (acc[mi][nj][2] + bg4.z) - miv * gg4.z + bn4.z;
            float v3 = inv * (acc[mi][nj][3] + bg4.w) - miv * gg4.w + bn4.w;
            float4 hv = h4[mi][nj];
            pm += v0 * hv.x + v1 * hv.y + v2 * hv.z + v3 * hv.w;
            ushort4 sv;
            sv.x = f2bfu(v0); sv.y = f2bfu(v1); sv.z = f2bfu(v2); sv.w = f2bfu(v3);
            if (ok) *(ushort4*)&zT[(size_t)e * 4096 + cb + j0] = sv;
        }
        pm += __shfl_xor(pm, 16);
        pm += __shfl_xor(pm, 32);
        if (ok && kg == 0) atomicAdd(&agg0[(size_t)sDst[e_local] * 64 + og], pm);
    }
}

// ---------------- msg: wave-per-edge DENSE reads of zT row (layout o*64+d) ----------------
__global__ __launch_bounds__(256) void msg_kernel(const unsigned short* __restrict__ zT,
                                                  const float* __restrict__ h,
                                                  const int* __restrict__ ei,
                                                  float* __restrict__ agg, int E) {
    int t = threadIdx.x;
    int w = t >> 6, lane = t & 63;
    int e = blockIdx.x * 4 + w;
    __shared__ float hL[4][64];
    __shared__ float oL[4][64];
    int src = ei[e];
    int dstn = ei[E + e];
    hL[w][lane] = h[(size_t)src * 64 + lane];
    __syncthreads();
    const uint4* zp = (const uint4*)(zT + (size_t)e * 4096);
    const int d0 = (lane & 7) * 8;
    const float* hp = &hL[w][d0];
    float h0 = hp[0], h1v = hp[1], h2 = hp[2], h3 = hp[3];
    float h4 = hp[4], h5 = hp[5], h6 = hp[6], h7 = hp[7];
    float accq[8];
#pragma unroll
    for (int q = 0; q < 8; q++) {
        uint4 v = zp[q * 64 + lane];
        float a;
        a  = __uint_as_float(v.x << 16) * h0 + __uint_as_float(v.x & 0xffff0000u) * h1v;
        a += __uint_as_float(v.y << 16) * h2 + __uint_as_float(v.y & 0xffff0000u) * h3;
        a += __uint_as_float(v.z << 16) * h4 + __uint_as_float(v.z & 0xffff0000u) * h5;
        a += __uint_as_float(v.w << 16) * h6 + __uint_as_float(v.w & 0xffff0000u) * h7;
        accq[q] = a;
    }
#pragma unroll
    for (int q = 0; q < 8; q++) {
        accq[q] += __shfl_xor(accq[q], 1);
        accq[q] += __shfl_xor(accq[q], 2);
        accq[q] += __shfl_xor(accq[q], 4);
    }
    if ((lane & 7) == 0) {
#pragma unroll
        for (int q = 0; q < 8; q++) oL[w][q * 8 + (lane >> 3)] = accq[q];
    }
    __syncthreads();
    atomicAdd(&agg[(size_t)dstn * 64 + lane], oL[w][lane]);
}

// ---------------- GRU cell over 8 nodes/block ----------------
__global__ __launch_bounds__(192) void gru_kernel(
    const float* __restrict__ agg, const float* __restrict__ counts, const float* __restrict__ cbias,
    const float* __restrict__ wih, const float* __restrict__ whh,
    const float* __restrict__ bih, const float* __restrict__ bhh, float* __restrict__ h, int N) {
    int t = threadIdx.x;
    int nb = blockIdx.x * 8;
    __shared__ __align__(16) float mL[8][64], hL[8][64], gxL[8][192], ghL[8][192];
    for (int idx = t; idx < 512; idx += 192) {
        int n = idx >> 6, k = idx & 63;
        int node = nb + n;
        float cnt = fmaxf(counts[node], 1.0f);
        mL[n][k] = fmaxf(agg[node * 64 + k] / cnt + cbias[k], 0.0f);
        hL[n][k] = h[node * 64 + k];
    }
    __syncthreads();
    {
        int j = t;
        float ax[8], ah[8];
#pragma unroll
        for (int n = 0; n < 8; n++) { ax[n] = 0.f; ah[n] = 0.f; }
        const float4* wi = (const float4*)(wih + j * 64);
        const float4* wh = (const float4*)(whh + j * 64);
#pragma unroll 4
        for (int k4 = 0; k4 < 16; k4++) {
            float4 wiv = wi[k4], whv = wh[k4];
#pragma unroll
            for (int n = 0; n < 8; n++) {
                ax[n] += dot4(wiv, *(const float4*)&mL[n][k4 * 4]);
                ah[n] += dot4(whv, *(const float4*)&hL[n][k4 * 4]);
            }
        }
        float bi = bih[j], bh = bhh[j];
#pragma unroll
        for (int n = 0; n < 8; n++) { gxL[n][j] = ax[n] + bi; ghL[n][j] = ah[n] + bh; }
    }
    __syncthreads();
    for (int idx = t; idx < 512; idx += 192) {
        int n = idx >> 6, k = idx & 63;
        int node = nb + n;
        float r = sigmoidf_(gxL[n][k] + ghL[n][k]);
        float zz = sigmoidf_(gxL[n][64 + k] + ghL[n][64 + k]);
        float nn = tanhf(gxL[n][128 + k] + r * ghL[n][128 + k]);
        h[node * 64 + k] = (1.0f - zz) * nn + zz * hL[n][k];
    }
}

// ---------------- Set2Set prep: cout + wc + lstm step-1 init, one kernel ----------------
__global__ __launch_bounds__(256) void coutprep_kernel(
    const float* __restrict__ h, const float* __restrict__ wih, const float* __restrict__ whh,
    const float* __restrict__ bih, const float* __restrict__ bhh,
    float* __restrict__ cout, float* __restrict__ wc,
    float* __restrict__ hl, float* __restrict__ cl, int N) {
    int t = threadIdx.x, nb = blockIdx.x * 8;
    __shared__ __align__(16) float oL[8][64];
    for (int idx = t; idx < 512; idx += 256) {
        int n = idx >> 6, k = idx & 63;
        oL[n][k] = h[(nb + n) * 64 + k];
    }
    __syncthreads();
    {
        float acc[8];
#pragma unroll
        for (int n = 0; n < 8; n++) acc[n] = 0.f;
        const float* wr = wih + t * 128 + 64;
#pragma unroll 4
        for (int k4 = 0; k4 < 16; k4++) {
            float4 w4 = *(const float4*)&wr[k4 * 4];
#pragma unroll
            for (int n = 0; n < 8; n++) acc[n] += dot4(w4, *(const float4*)&oL[n][k4 * 4]);
        }
#pragma unroll
        for (int n = 0; n < 8; n++) cout[(size_t)(nb + n) * 256 + t] = acc[n];
    }
    if (blockIdx.x < 64) {
        int id = blockIdx.x * 256 + t;
        int j = id >> 6, k = id & 63;
        wc[id] = wih[j * 128 + k] + whh[id];
    }
    if (t < 64) {
        float gi = bih[t] + bhh[t];
        float gg = bih[128 + t] + bhh[128 + t];
        float go = bih[192 + t] + bhh[192 + t];
        float c0 = sigmoidf_(gi) * tanhf(gg);
        float h0 = sigmoidf_(go) * tanhf(c0);
#pragma unroll
        for (int n = 0; n < 8; n++) {
            cl[(nb + n) * 64 + t] = c0;
            hl[(nb + n) * 64 + t] = h0;
        }
    }
}

// ---------------- LSTM steps 2,3 ----------------
__global__ __launch_bounds__(256) void lstm_step_kernel(const float* __restrict__ wc,
                                                        const float* __restrict__ bih,
                                                        const float* __restrict__ bhh,
                                                        const float* __restrict__ cout,
                                                        float* __restrict__ hl,
                                                        float* __restrict__ cl, int N) {
    int t = threadIdx.x, nb = blockIdx.x * 8;
    __shared__ __align__(16) float hlL[8][64];
    __shared__ float gL[8][256];
    for (int idx = t; idx < 512; idx += 256) {
        int n = idx >> 6, k = idx & 63;
        hlL[n][k] = hl[(nb + n) * 64 + k];
    }
    __syncthreads();
    {
        float acc[8];
#pragma unroll
        for (int n = 0; n < 8; n++) acc[n] = 0.f;
        const float4* w4p = (const float4*)(wc + t * 64);
#pragma unroll 4
        for (int k4 = 0; k4 < 16; k4++) {
            float4 w4 = w4p[k4];
#pragma unroll
            for (int n = 0; n < 8; n++) acc[n] += dot4(w4, *(const float4*)&hlL[n][k4 * 4]);
        }
        float bs = bih[t] + bhh[t];
#pragma unroll
        for (int n = 0; n < 8; n++) gL[n][t] = acc[n] + cout[(size_t)(nb + n) * 256 + t] + bs;
    }
    __syncthreads();
    for (int idx = t; idx < 512; idx += 256) {
        int n = idx >> 6, k = idx & 63;
        int node = nb + n;
        float gi = gL[n][k], gf = gL[n][64 + k], gg = gL[n][128 + k], go = gL[n][192 + k];
        float c = sigmoidf_(gf) * cl[node * 64 + k] + sigmoidf_(gi) * tanhf(gg);
        cl[node * 64 + k] = c;
        hl[node * 64 + k] = sigmoidf_(go) * tanhf(c);
    }
}

// ---------------- head: persistent blocks, LDS-staged bf16 W1 ----------------
__global__ __launch_bounds__(256) void head_kernel(
    const float* __restrict__ h, const float* __restrict__ hl, const int* __restrict__ ti,
    const int* __restrict__ tc, const float* __restrict__ w1, const float* __restrict__ b1,
    const float* __restrict__ g1, const float* __restrict__ bn1, const float* __restrict__ w2,
    const float* __restrict__ b2, float* __restrict__ out, int P) {
    __shared__ uint2 w1q[6144];
    __shared__ float catL[4][384];
    int t = threadIdx.x;
    const float4* w1f4 = (const float4*)w1;
#pragma unroll
    for (int i = 0; i < 24; i++) {
        int f = t + i * 256;
        float4 v = w1f4[f];
        int j = f / 96, k4 = f - j * 96;
        w1q[k4 * 64 + j] = make_uint2(pack2bf(v.x, v.y), pack2bf(v.z, v.w));
    }
    int j = t & 63, pl = t >> 6;
    float b1j = b1[j], g1j = g1[j], bnj = bn1[j];
    __syncthreads();

    for (int pb = blockIdx.x * 4; pb < P; pb += gridDim.x * 4) {
#pragma unroll
        for (int i = 0; i < 6; i++) {
            int idx = t + i * 256;
            int p = idx / 384, kk = idx - p * 384;
            int pair = pb + p;
            if (pair >= P) pair = P - 1;
            int a0 = ti[pair], a1 = ti[P + pair];
            int s = kk >> 6, k = kk & 63;
            float v;
            if (s == 0 || s == 3) v = h[a0 * 64 + k];
            else if (s == 1 || s == 5) v = h[a1 * 64 + k];
            else if (s == 2) v = hl[a0 * 64 + k];
            else v = hl[a1 * 64 + k];
            catL[p][kk] = v;
        }
        __syncthreads();
        int pair = pb + pl;
        float acc = b1j;
#pragma unroll 8
        for (int k4 = 0; k4 < 96; k4++) {
            uint2 wv = w1q[k4 * 64 + j];
            float4 c = *(const float4*)&catL[pl][k4 * 4];
            acc += __uint_as_float(wv.x << 16) * c.x + __uint_as_float(wv.x & 0xffff0000u) * c.y;
            acc += __uint_as_float(wv.y << 16) * c.z + __uint_as_float(wv.y & 0xffff0000u) * c.w;
        }
        float s1 = acc, s2v = acc * acc;
#pragma unroll
        for (int m = 32; m >= 1; m >>= 1) { s1 += __shfl_xor(s1, m); s2v += __shfl_xor(s2v, m); }
        float mu = s1 * (1.0f / 64.0f);
        float var = fmaxf(s2v * (1.0f / 64.0f) - mu * mu, 0.0f);
        float p1 = fmaxf((acc - mu) * rsqrtf(var + EPS_LN) * g1j + bnj, 0.0f);
        int cls = tc[pair < P ? pair : P - 1];
        float part = p1 * w2[cls * 64 + j];
#pragma unroll
        for (int m = 32; m >= 1; m >>= 1) part += __shfl_xor(part, m);
        if (j == 0 && pair < P) out[pair] = part + b2[cls];
        __syncthreads();
    }
}

extern "C" void kernel_launch(void* const* d_in, const int* in_sizes, int n_in,
                              void* d_out, int out_size, void* d_ws, size_t ws_size,
                              hipStream_t stream) {
    const float* x = (const float*)d_in[0];
    const float* edge_attr = (const float*)d_in[1];
    const float* lin0_w = (const float*)d_in[2];
    const float* lin0_b = (const float*)d_in[3];
    const float* enn_w1 = (const float*)d_in[4];
    const float* enn_b1 = (const float*)d_in[5];
    const float* enn_g1 = (const float*)d_in[6];
    const float* enn_b1n = (const float*)d_in[7];
    const float* enn_w2 = (const float*)d_in[8];
    const float* enn_b2 = (const float*)d_in[9];
    const float* enn_g2 = (const float*)d_in[10];
    const float* enn_b2n = (const float*)d_in[11];
    const float* conv_bias = (const float*)d_in[12];
    const float* gru_w_ih = (const float*)d_in[13];
    const float* gru_w_hh = (const float*)d_in[14];
    const float* gru_b_ih = (const float*)d_in[15];
    const float* gru_b_hh = (const float*)d_in[16];
    const float* lstm_w_ih = (const float*)d_in[17];
    const float* lstm_w_hh = (const float*)d_in[18];
    const float* lstm_b_ih = (const float*)d_in[19];
    const float* lstm_b_hh = (const float*)d_in[20];
    const float* lin1_w = (const float*)d_in[21];
    const float* lin1_b = (const float*)d_in[22];
    const float* lin1_g = (const float*)d_in[23];
    const float* lin1_bn = (const float*)d_in[24];
    const float* lin2_w = (const float*)d_in[25];
    const float* lin2_b = (const float*)d_in[26];
    const int* edge_index = (const int*)d_in[27];
    const int* target_index = (const int*)d_in[28];
    const int* target_class = (const int*)d_in[29];

    const int N = in_sizes[0] / 16;
    const int E = in_sizes[27] / 2;
    const int P = in_sizes[29];

    size_t off = 0;
    auto carve = [&](size_t bytes) {
        void* p = (char*)d_ws + off;
        off += (bytes + 255) & ~(size_t)255;
        return p;
    };
    unsigned short* zbuf = (unsigned short*)carve((size_t)E * 4096 * 2);  // ew bf16 [e][o*64+d]
    unsigned short* e1h = (unsigned short*)carve((size_t)E * 128 * 2);    // pre-swizzled
    unsigned short* e1l = (unsigned short*)carve((size_t)E * 128 * 2);    // pre-swizzled
    unsigned short* w2gp = (unsigned short*)carve((size_t)4096 * 128 * 2);  // chunk-permuted+swz
    float* b2g = (float*)carve((size_t)4096 * 4);
    float* hbuf = (float*)carve((size_t)N * 64 * 4);
    float* counts = (float*)carve((size_t)N * 4 + (size_t)3 * N * 64 * 4);
    float* agg0 = counts + N;
    float* agg1 = agg0 + (size_t)N * 64;
    float* agg2 = agg1 + (size_t)N * 64;
    float* hl = (float*)carve((size_t)N * 64 * 4);
    float* cl = (float*)carve((size_t)N * 64 * 4);
    float* cout_b = (float*)carve((size_t)N * 256 * 4);
    float* wc = (float*)carve((size_t)256 * 64 * 4);
    float* stats = (float*)carve((size_t)E * 2 * 4);
    unsigned short* mb = (unsigned short*)carve((size_t)128 * 128 * 2);
    float* varr = (float*)carve((size_t)128 * 4);
    float* cw = (float*)carve((size_t)128 * 4);
    float* sbc = (float*)carve((size_t)2 * 4);
    float* pv = (float*)carve((size_t)256 * 128 * 4);
    float* pcw = (float*)carve((size_t)256 * 128 * 4);
    float* psb = (float*)carve((size_t)256 * 4);
    float* pc = (float*)carve((size_t)256 * 4);
    float* pMT = (float*)carve((size_t)256 * 128 * 128 * 4);
    (void)ws_size;

    hipMemsetAsync(counts, 0, (size_t)N * 4 + (size_t)3 * N * 64 * 4, stream);
    init_kernel<<<(N * 64 + 255) / 256, 256, 0, stream>>>(x, lin0_w, lin0_b, hbuf, edge_index,
                                                          counts, N, E);
    edge_nn1_kernel<<<E, 128, 0, stream>>>(edge_attr, enn_w1, enn_b1, enn_g1, enn_b1n, e1h, e1l, E);
    mpart_kernel<<<256, 128, 0, stream>>>(enn_w2, enn_b2, enn_g2, w2gp, b2g, pMT, pv, pcw, psb, pc);
    mreduce_kernel<<<64, 256, 0, stream>>>(pMT, pv, pcw, psb, pc, mb, varr, cw, sbc);
    stats_kernel<<<(E + 63) / 64, 256, 0, stream>>>(e1h, e1l, mb, cw, varr, sbc, stats, E);
    {
        dim3 g(32, (E + 63) / 64);  // x = col-chunk fastest -> e1 tile stays L2-hot
        zgemm_final<<<g, 256, 0, stream>>>(e1h, w2gp, b2g, enn_g2, enn_b2n, stats, hbuf,
                                           edge_index, agg0, zbuf, E);
    }

    // iteration 1: agg0 computed by zgemm_final's fused epilogue (fp32-exact)
    gru_kernel<<<N / 8, 192, 0, stream>>>(agg0, counts, conv_bias, gru_w_ih, gru_w_hh,
                                          gru_b_ih, gru_b_hh, hbuf, N);
    float* aggs[2] = {agg1, agg2};
    for (int it = 0; it < 2; it++) {
        msg_kernel<<<E / 4, 256, 0, stream>>>(zbuf, hbuf, edge_index, aggs[it], E);
        gru_kernel<<<N / 8, 192, 0, stream>>>(aggs[it], counts, conv_bias, gru_w_ih, gru_w_hh,
                                              gru_b_ih, gru_b_hh, hbuf, N);
    }

    coutprep_kernel<<<N / 8, 256, 0, stream>>>(hbuf, lstm_w_ih, lstm_w_hh, lstm_b_ih, lstm_b_hh,
                                               cout_b, wc, hl, cl, N);
    lstm_step_kernel<<<N / 8, 256, 0, stream>>>(wc, lstm_b_ih, lstm_b_hh, cout_b, hl, cl, N);
    lstm_step_kernel<<<N / 8, 256, 0, stream>>>(wc, lstm_b_ih, lstm_b_hh, cout_b, hl, cl, N);

    head_kernel<<<512, 256, 0, stream>>>(hbuf, hl, target_index, target_class, lin1_w, lin1_b,
                                         lin1_g, lin1_bn, lin2_w, lin2_b, (float*)d_out, P);
}

// Round 13
// 373.531 us; speedup vs baseline: 1.0965x; 1.0965x over previous
//
#include <hip/hip_runtime.h>
#include <hip/hip_bf16.h>

#define EPS_LN 1e-5f
#define ZTILES 4

typedef __attribute__((ext_vector_type(8))) short bf16x8;
typedef __attribute__((ext_vector_type(4))) float f32x4;

__device__ __forceinline__ float dot4(float4 a, float4 b) {
    return a.x * b.x + a.y * b.y + a.z * b.z + a.w * b.w;
}
__device__ __forceinline__ float sigmoidf_(float x) { return 1.0f / (1.0f + expf(-x)); }

__device__ __forceinline__ float bfu2f(unsigned short u) {
    unsigned v = ((unsigned)u) << 16;
    float f;
    __builtin_memcpy(&f, &v, 4);
    return f;
}
__device__ __forceinline__ unsigned short f2bfu(float f) {
    __hip_bfloat16 h = __float2bfloat16(f);
    unsigned short u;
    __builtin_memcpy(&u, &h, 2);
    return u;
}
__device__ __forceinline__ unsigned pack2bf(float a, float b) {
    return (unsigned)f2bfu(a) | ((unsigned)f2bfu(b) << 16);
}
// async global->LDS 16B copy (vmcnt-tracked; __syncthreads drains)
__device__ __forceinline__ void async_cp16(void* lds, const void* g) {
    __builtin_amdgcn_global_load_lds((const __attribute__((address_space(1))) void*)g,
                                     (__attribute__((address_space(3))) void*)lds, 16, 0, 0);
}

// ---------------- lin0 + degree counts fused ----------------
__global__ void init_kernel(const float* __restrict__ x, const float* __restrict__ w,
                            const float* __restrict__ b, float* __restrict__ h,
                            const int* __restrict__ ei, float* __restrict__ counts,
                            int N, int E) {
    int id = blockIdx.x * blockDim.x + threadIdx.x;
    if (id < N * 64) {
        int n = id >> 6, o = id & 63;
        const float* xr = x + n * 16;
        const float* wr = w + o * 16;
        float acc = b[o];
#pragma unroll
        for (int k = 0; k < 16; k++) acc += xr[k] * wr[k];
        h[id] = fmaxf(acc, 0.0f);
    }
    if (id < E) atomicAdd(&counts[ei[E + id]], 1.0f);
}

// ---------------- edge NN layer 1 -> e1 hi/lo bf16, PRE-SWIZZLED storage ----------------
__global__ __launch_bounds__(128) void edge_nn1_kernel(
    const float* __restrict__ ea, const float* __restrict__ w1, const float* __restrict__ b1,
    const float* __restrict__ g1, const float* __restrict__ b1n,
    unsigned short* __restrict__ e1h, unsigned short* __restrict__ e1l, int E) {
    int e = blockIdx.x, j = threadIdx.x;
    float a0 = ea[e * 4 + 0], a1 = ea[e * 4 + 1], a2 = ea[e * 4 + 2], a3 = ea[e * 4 + 3];
    const float* wr = w1 + j * 4;
    float z = b1[j] + a0 * wr[0] + a1 * wr[1] + a2 * wr[2] + a3 * wr[3];
    float s = z, s2 = z * z;
#pragma unroll
    for (int m = 32; m >= 1; m >>= 1) { s += __shfl_xor(s, m); s2 += __shfl_xor(s2, m); }
    __shared__ float ls[2], ls2[2];
    int wv = j >> 6;
    if ((j & 63) == 0) { ls[wv] = s; ls2[wv] = s2; }
    __syncthreads();
    float S = ls[0] + ls[1], S2 = ls2[0] + ls2[1];
    float mu = S * (1.0f / 128.0f);
    float var = fmaxf(S2 * (1.0f / 128.0f) - mu * mu, 0.0f);
    float inv = rsqrtf(var + EPS_LN);
    float v = fmaxf((z - mu) * inv * g1[j] + b1n[j], 0.0f);
    unsigned short hi = f2bfu(v);
    unsigned short lo = f2bfu(v - bfu2f(hi));
    int jp = j ^ ((e & 7) << 3);
    e1h[e * 128 + jp] = hi;
    e1l[e * 128 + jp] = lo;
}

// ---------------- M partials + W2 fold into w2gp (chunk-permuted + swizzled) ----------------
__global__ __launch_bounds__(128) void mpart_kernel(const float* __restrict__ w2,
                                                    const float* __restrict__ b2,
                                                    const float* __restrict__ g2,
                                                    unsigned short* __restrict__ w2gp,
                                                    float* __restrict__ b2g,
                                                    float* __restrict__ pMT, float* __restrict__ pv,
                                                    float* __restrict__ pcw, float* __restrict__ psb,
                                                    float* __restrict__ pc) {
    __shared__ float wL[16][128];
    __shared__ float b2L[16];
    int t = threadIdx.x, b = blockIdx.x;
#pragma unroll
    for (int i = 0; i < 16; i++) {
        int idx = t + i * 128;
        wL[idx >> 7][idx & 127] = w2[(size_t)(b * 16 + (idx >> 7)) * 128 + (idx & 127)];
    }
    if (t < 16) b2L[t] = b2[b * 16 + t];
    __syncthreads();
#pragma unroll
    for (int o = 0; o < 16; o++) {
        int r = b * 16 + o;
        int x = (r & 63) >> 1;
        int jj = (r >> 6) + ((r & 1) << 6);
        w2gp[(size_t)x * 16384 + jj * 128 + (t ^ ((jj & 7) << 3))] = f2bfu(wL[o][t] * g2[r]);
    }
    if (t < 16) b2g[b * 16 + t] = b2L[t] * g2[b * 16 + t];
    int j = t;
    float wj[16];
#pragma unroll
    for (int o = 0; o < 16; o++) wj[o] = wL[o][j];
    float pvj = 0.f, pcwj = 0.f;
#pragma unroll
    for (int o = 0; o < 16; o++) { pvj += wj[o] * b2L[o]; pcwj += wj[o]; }
    for (int i4 = 0; i4 < 32; i4++) {
        float4 a = {0.f, 0.f, 0.f, 0.f};
#pragma unroll
        for (int o = 0; o < 16; o++) {
            float4 w4 = *(const float4*)&wL[o][i4 * 4];
            a.x += wj[o] * w4.x; a.y += wj[o] * w4.y;
            a.z += wj[o] * w4.z; a.w += wj[o] * w4.w;
        }
        *(float4*)&pMT[((size_t)b * 128 + j) * 128 + i4 * 4] = a;
    }
    pv[b * 128 + j] = pvj;
    pcw[b * 128 + j] = pcwj;
    if (t == 0) {
        float sb = 0.f, cc = 0.f;
#pragma unroll
        for (int o = 0; o < 16; o++) { sb += b2L[o]; cc += b2L[o] * b2L[o]; }
        psb[b] = sb;
        pc[b] = cc;
    }
}

// ---------------- reduce partials -> Mb (bf16), varr, cw, sbc ----------------
__global__ __launch_bounds__(256) void mreduce_kernel(const float* __restrict__ pMT,
                                                      const float* __restrict__ pv,
                                                      const float* __restrict__ pcw,
                                                      const float* __restrict__ psb,
                                                      const float* __restrict__ pc,
                                                      unsigned short* __restrict__ mb,
                                                      float* __restrict__ varr,
                                                      float* __restrict__ cw,
                                                      float* __restrict__ sbc) {
    int fid = blockIdx.x * 256 + threadIdx.x;  // < 16384
    float s = 0.f;
    int j = fid >> 7, i = fid & 127;
    for (int b = 0; b < 256; b++) s += pMT[((size_t)b * 128 + j) * 128 + i];
    mb[fid] = f2bfu(s);
    if (fid < 128) {
        float sv = 0.f, sc = 0.f;
        for (int b = 0; b < 256; b++) { sv += pv[b * 128 + fid]; sc += pcw[b * 128 + fid]; }
        varr[fid] = sv;
        cw[fid] = sc;
    }
    if (fid == 0) {
        float sb = 0.f, cc = 0.f;
        for (int b = 0; b < 256; b++) { sb += psb[b]; cc += pc[b]; }
        sbc[0] = sb;
        sbc[1] = cc;
    }
}

// ---------------- per-edge LN stats via quadratic form, MFMA ----------------
__global__ __launch_bounds__(256) void stats_kernel(
    const unsigned short* __restrict__ e1h, const unsigned short* __restrict__ e1l,
    const unsigned short* __restrict__ mb, const float* __restrict__ cw,
    const float* __restrict__ varr, const float* __restrict__ sbc,
    float* __restrict__ stats, int E) {
    __shared__ __align__(16) unsigned char smem[65536];
    const int t = threadIdx.x;
    const int eb = blockIdx.x * 64;
#pragma unroll
    for (int r = 0; r < 4; r++) {
        int idx = t + r * 256;
        int row = idx >> 4, kseg = idx & 15;
        int er = eb + row;
        if (er >= E) er = E - 1;
        uint4 vh = *(const uint4*)&e1h[(size_t)er * 128 + kseg * 8];
        uint4 vl = *(const uint4*)&e1l[(size_t)er * 128 + kseg * 8];
        int off = row * 256 + kseg * 16;  // linear: source is pre-swizzled
        *(uint4*)(smem + off) = vh;
        *(uint4*)(smem + 16384 + off) = vl;
    }
#pragma unroll
    for (int r = 0; r < 8; r++) {
        int idx = t + r * 256;
        int row = idx >> 4, kseg = idx & 15;
        uint4 v = *(const uint4*)&mb[(size_t)row * 128 + kseg * 8];
        *(uint4*)(smem + 32768 + row * 256 + ((kseg * 16) ^ ((row & 7) << 4))) = v;
    }
    __syncthreads();
    const int w = t >> 6, lane = t & 63;
    const int wrow = w * 16;
    const int r16 = lane & 15, kg = lane >> 4;
    f32x4 tacc[8];
#pragma unroll
    for (int nj = 0; nj < 8; nj++) tacc[nj] = (f32x4){0.f, 0.f, 0.f, 0.f};
#pragma unroll
    for (int ks = 0; ks < 4; ks++) {
        int arow = wrow + r16;
        int koff = ks * 64 + kg * 16;
        bf16x8 ah = *(const bf16x8*)(smem + arow * 256 + (koff ^ ((arow & 7) << 4)));
        bf16x8 al = *(const bf16x8*)(smem + 16384 + arow * 256 + (koff ^ ((arow & 7) << 4)));
#pragma unroll
        for (int nj = 0; nj < 8; nj++) {
            int brow = nj * 16 + r16;
            bf16x8 bf = *(const bf16x8*)(smem + 32768 + brow * 256 + (koff ^ ((brow & 7) << 4)));
            tacc[nj] = __builtin_amdgcn_mfma_f32_16x16x32_bf16(ah, bf, tacc[nj], 0, 0, 0);
            tacc[nj] = __builtin_amdgcn_mfma_f32_16x16x32_bf16(al, bf, tacc[nj], 0, 0, 0);
        }
    }
    __syncthreads();
#pragma unroll
    for (int nj = 0; nj < 8; nj++)
#pragma unroll
        for (int r = 0; r < 4; r++) {
            int row = wrow + kg * 4 + r, col = nj * 16 + r16;
            *(float*)(smem + 32768 + row * 512 + col * 4) = tacc[nj][r];
        }
    __syncthreads();
    int el = t >> 2, q = t & 3;
    float s2p = 0.f, sp = 0.f, svp = 0.f;
    for (int kk = 0; kk < 32; kk++) {
        int k = q * 32 + kk;
        int boff = el * 256 + ((2 * k) ^ ((el & 7) << 4));
        float e1v = bfu2f(*(const unsigned short*)(smem + boff)) +
                    bfu2f(*(const unsigned short*)(smem + 16384 + boff));
        float tv = *(const float*)(smem + 32768 + el * 512 + k * 4);
        s2p += tv * e1v;
        sp += e1v * cw[k];
        svp += e1v * varr[k];
    }
    s2p += __shfl_xor(s2p, 1); s2p += __shfl_xor(s2p, 2);
    sp += __shfl_xor(sp, 1);   sp += __shfl_xor(sp, 2);
    svp += __shfl_xor(svp, 1); svp += __shfl_xor(svp, 2);
    if (q == 0) {
        int e = eb + el;
        if (e < E) {
            float S = sp + sbc[0];
            float S2 = s2p + 2.f * svp + sbc[1];
            float mu = S * (1.0f / 4096.0f);
            float var = fmaxf(S2 * (1.0f / 4096.0f) - mu * mu, 0.0f);
            float inv = rsqrtf(var + EPS_LN);
            stats[e * 2 + 0] = inv;
            stats[e * 2 + 1] = mu * inv;
        }
    }
}

// ---------------- z-GEMM, B-resident multi-tile pipeline ----
// grid (32, ceil(NT/ZTILES)). Block stages B ONCE (32KB, global_load_lds), holds
// bfrag[4][4] in registers, loops ZTILES edge-tiles: afrag ds_reads + 32 MFMA;
// barrier; prefetch next A (overlaps epilogue); epilogue + direct ushort4 stores; barrier.
__global__ __launch_bounds__(256) void zgemm_final(
    const unsigned short* __restrict__ e1h,
    const unsigned short* __restrict__ w2gp, const float* __restrict__ b2g,
    const float* __restrict__ g2, const float* __restrict__ b2n,
    const float* __restrict__ stats, unsigned short* __restrict__ zT, int E) {
    __shared__ __align__(16) unsigned char smem[49152];  // A [0,16K) + B [16K,48K)
    __shared__ float cBg[128], cGg[128], cBn[128];
    const int t = threadIdx.x;
    const int w = t >> 6, lane = t & 63;
    const int cb = blockIdx.x * 128;
    const int o0 = blockIdx.x * 2;
    const int soff = w * 1024 + lane * 16;
    int eb = blockIdx.y * (ZTILES * 64);
    // ---- stage B once + A tile 0 (async) ----
    {
        const char* srcB = (const char*)w2gp + (size_t)blockIdx.x * 32768 + soff;
        char* dstB = (char*)smem + 16384 + soff;
#pragma unroll
        for (int i = 0; i < 8; i++) async_cp16(dstB + i * 4096, srcB + i * 4096);
        const char* srcA = (const char*)e1h + (size_t)eb * 256 + soff;
        char* dstA = (char*)smem + soff;
#pragma unroll
        for (int i = 0; i < 4; i++) async_cp16(dstA + i * 4096, srcA + i * 4096);
    }
    if (t < 128) {
        int sj = ((t & 63) << 6) + o0 + (t >> 6);
        cBg[t] = b2g[sj];
        cGg[t] = g2[sj];
        cBn[t] = b2n[sj];
    }
    __syncthreads();  // drains vmcnt -> B + A(0) ready
    const int wrow = (w >> 1) * 32, wcol = (w & 1) * 64;
    const int r16 = lane & 15, kg = lane >> 4;
    // ---- bfrag register-resident for all tiles ----
    bf16x8 bfrag[4][4];
#pragma unroll
    for (int nj = 0; nj < 4; nj++)
#pragma unroll
        for (int ks = 0; ks < 4; ks++) {
            int row = wcol + nj * 16 + r16;
            int koff = ks * 64 + kg * 16;
            bfrag[nj][ks] = *(const bf16x8*)(smem + 16384 + row * 256 + (koff ^ ((row & 7) << 4)));
        }
#pragma unroll 1
    for (int ti = 0; ti < ZTILES; ti++, eb += 64) {
        if (eb >= E) break;
        // early per-edge stats loads (consumed in epilogue; hidden under MFMA)
        float sInvR[2], sMivR[2];
#pragma unroll
        for (int mi = 0; mi < 2; mi++) {
            int eg = eb + wrow + mi * 16 + r16;
            if (eg >= E) eg = E - 1;
            sInvR[mi] = stats[eg * 2 + 0];
            sMivR[mi] = stats[eg * 2 + 1];
        }
        f32x4 acc[2][4];
#pragma unroll
        for (int mi = 0; mi < 2; mi++)
#pragma unroll
            for (int nj = 0; nj < 4; nj++) acc[mi][nj] = (f32x4){0.f, 0.f, 0.f, 0.f};
#pragma unroll
        for (int ks = 0; ks < 4; ks++) {
            int koff = ks * 64 + kg * 16;
            bf16x8 af[2];
#pragma unroll
            for (int mi = 0; mi < 2; mi++) {
                int row = wrow + mi * 16 + r16;
                af[mi] = *(const bf16x8*)(smem + row * 256 + (koff ^ ((row & 7) << 4)));
            }
#pragma unroll
            for (int mi = 0; mi < 2; mi++)
#pragma unroll
                for (int nj = 0; nj < 4; nj++)
                    acc[mi][nj] = __builtin_amdgcn_mfma_f32_16x16x32_bf16(
                        bfrag[nj][ks], af[mi], acc[mi][nj], 0, 0, 0);  // SWAPPED: (A.B^T)^T
        }
        __syncthreads();  // all waves' A ds_reads complete -> safe to overwrite A
        // prefetch next A tile (overlaps epilogue + stores)
        if (ti + 1 < ZTILES && eb + 64 < E) {
            const char* srcA = (const char*)e1h + (size_t)(eb + 64) * 256 + soff;
            char* dstA = (char*)smem + soff;
#pragma unroll
            for (int i = 0; i < 4; i++) async_cp16(dstA + i * 4096, srcA + i * 4096);
        }
        // ---- epilogue: lane owns (edge = wrow+mi*16+r16, cols j0..j0+3) ----
#pragma unroll
        for (int mi = 0; mi < 2; mi++) {
            int e_local = wrow + mi * 16 + r16;
            int e = eb + e_local;
            float inv = sInvR[mi], miv = sMivR[mi];
            bool ok = (e < E);
#pragma unroll
            for (int nj = 0; nj < 4; nj++) {
                int j0 = wcol + nj * 16 + kg * 4;
                float4 bg4 = *(const float4*)&cBg[j0];
                float4 gg4 = *(const float4*)&cGg[j0];
                float4 bn4 = *(const float4*)&cBn[j0];
                ushort4 sv;
                sv.x = f2bfu(inv * (acc[mi][nj][0] + bg4.x) - miv * gg4.x + bn4.x);
                sv.y = f2bfu(inv * (acc[mi][nj][1] + bg4.y) - miv * gg4.y + bn4.y);
                sv.z = f2bfu(inv * (acc[mi][nj][2] + bg4.z) - miv * gg4.z + bn4.z);
                sv.w = f2bfu(inv * (acc[mi][nj][3] + bg4.w) - miv * gg4.w + bn4.w);
                if (ok) *(ushort4*)&zT[(size_t)e * 4096 + cb + j0] = sv;
            }
        }
        __syncthreads();  // drains prefetch -> next tile's A ready
    }
}

// ---------------- msg: wave-per-edge DENSE reads of zT row (layout o*64+d) ----------------
__global__ __launch_bounds__(256) void msg_kernel(const unsigned short* __restrict__ zT,
                                                  const float* __restrict__ h,
                                                  const int* __restrict__ ei,
                                                  float* __restrict__ agg, int E) {
    int t = threadIdx.x;
    int w = t >> 6, lane = t & 63;
    int e = blockIdx.x * 4 + w;
    __shared__ float hL[4][64];
    __shared__ float oL[4][64];
    int src = ei[e];
    int dstn = ei[E + e];
    hL[w][lane] = h[(size_t)src * 64 + lane];
    __syncthreads();
    const uint4* zp = (const uint4*)(zT + (size_t)e * 4096);
    const int d0 = (lane & 7) * 8;
    const float* hp = &hL[w][d0];
    float h0 = hp[0], h1v = hp[1], h2 = hp[2], h3 = hp[3];
    float h4 = hp[4], h5 = hp[5], h6 = hp[6], h7 = hp[7];
    float accq[8];
#pragma unroll
    for (int q = 0; q < 8; q++) {
        uint4 v = zp[q * 64 + lane];
        float a;
        a  = __uint_as_float(v.x << 16) * h0 + __uint_as_float(v.x & 0xffff0000u) * h1v;
        a += __uint_as_float(v.y << 16) * h2 + __uint_as_float(v.y & 0xffff0000u) * h3;
        a += __uint_as_float(v.z << 16) * h4 + __uint_as_float(v.z & 0xffff0000u) * h5;
        a += __uint_as_float(v.w << 16) * h6 + __uint_as_float(v.w & 0xffff0000u) * h7;
        accq[q] = a;
    }
#pragma unroll
    for (int q = 0; q < 8; q++) {
        accq[q] += __shfl_xor(accq[q], 1);
        accq[q] += __shfl_xor(accq[q], 2);
        accq[q] += __shfl_xor(accq[q], 4);
    }
    if ((lane & 7) == 0) {
#pragma unroll
        for (int q = 0; q < 8; q++) oL[w][q * 8 + (lane >> 3)] = accq[q];
    }
    __syncthreads();
    atomicAdd(&agg[(size_t)dstn * 64 + lane], oL[w][lane]);
}

// ---------------- GRU cell over 8 nodes/block ----------------
__global__ __launch_bounds__(192) void gru_kernel(
    const float* __restrict__ agg, const float* __restrict__ counts, const float* __restrict__ cbias,
    const float* __restrict__ wih, const float* __restrict__ whh,
    const float* __restrict__ bih, const float* __restrict__ bhh, float* __restrict__ h, int N) {
    int t = threadIdx.x;
    int nb = blockIdx.x * 8;
    __shared__ __align__(16) float mL[8][64], hL[8][64], gxL[8][192], ghL[8][192];
    for (int idx = t; idx < 512; idx += 192) {
        int n = idx >> 6, k = idx & 63;
        int node = nb + n;
        float cnt = fmaxf(counts[node], 1.0f);
        mL[n][k] = fmaxf(agg[node * 64 + k] / cnt + cbias[k], 0.0f);
        hL[n][k] = h[node * 64 + k];
    }
    __syncthreads();
    {
        int j = t;
        float ax[8], ah[8];
#pragma unroll
        for (int n = 0; n < 8; n++) { ax[n] = 0.f; ah[n] = 0.f; }
        const float4* wi = (const float4*)(wih + j * 64);
        const float4* wh = (const float4*)(whh + j * 64);
#pragma unroll 4
        for (int k4 = 0; k4 < 16; k4++) {
            float4 wiv = wi[k4], whv = wh[k4];
#pragma unroll
            for (int n = 0; n < 8; n++) {
                ax[n] += dot4(wiv, *(const float4*)&mL[n][k4 * 4]);
                ah[n] += dot4(whv, *(const float4*)&hL[n][k4 * 4]);
            }
        }
        float bi = bih[j], bh = bhh[j];
#pragma unroll
        for (int n = 0; n < 8; n++) { gxL[n][j] = ax[n] + bi; ghL[n][j] = ah[n] + bh; }
    }
    __syncthreads();
    for (int idx = t; idx < 512; idx += 192) {
        int n = idx >> 6, k = idx & 63;
        int node = nb + n;
        float r = sigmoidf_(gxL[n][k] + ghL[n][k]);
        float zz = sigmoidf_(gxL[n][64 + k] + ghL[n][64 + k]);
        float nn = tanhf(gxL[n][128 + k] + r * ghL[n][128 + k]);
        h[node * 64 + k] = (1.0f - zz) * nn + zz * hL[n][k];
    }
}

// ---------------- Set2Set prep: cout + wc + lstm step-1 init, one kernel ----------------
__global__ __launch_bounds__(256) void coutprep_kernel(
    const float* __restrict__ h, const float* __restrict__ wih, const float* __restrict__ whh,
    const float* __restrict__ bih, const float* __restrict__ bhh,
    float* __restrict__ cout, float* __restrict__ wc,
    float* __restrict__ hl, float* __restrict__ cl, int N) {
    int t = threadIdx.x, nb = blockIdx.x * 8;
    __shared__ __align__(16) float oL[8][64];
    for (int idx = t; idx < 512; idx += 256) {
        int n = idx >> 6, k = idx & 63;
        oL[n][k] = h[(nb + n) * 64 + k];
    }
    __syncthreads();
    {
        float acc[8];
#pragma unroll
        for (int n = 0; n < 8; n++) acc[n] = 0.f;
        const float* wr = wih + t * 128 + 64;
#pragma unroll 4
        for (int k4 = 0; k4 < 16; k4++) {
            float4 w4 = *(const float4*)&wr[k4 * 4];
#pragma unroll
            for (int n = 0; n < 8; n++) acc[n] += dot4(w4, *(const float4*)&oL[n][k4 * 4]);
        }
#pragma unroll
        for (int n = 0; n < 8; n++) cout[(size_t)(nb + n) * 256 + t] = acc[n];
    }
    if (blockIdx.x < 64) {
        int id = blockIdx.x * 256 + t;
        int j = id >> 6, k = id & 63;
        wc[id] = wih[j * 128 + k] + whh[id];
    }
    if (t < 64) {
        float gi = bih[t] + bhh[t];
        float gg = bih[128 + t] + bhh[128 + t];
        float go = bih[192 + t] + bhh[192 + t];
        float c0 = sigmoidf_(gi) * tanhf(gg);
        float h0 = sigmoidf_(go) * tanhf(c0);
#pragma unroll
        for (int n = 0; n < 8; n++) {
            cl[(nb + n) * 64 + t] = c0;
            hl[(nb + n) * 64 + t] = h0;
        }
    }
}

// ---------------- LSTM steps 2,3 ----------------
__global__ __launch_bounds__(256) void lstm_step_kernel(const float* __restrict__ wc,
                                                        const float* __restrict__ bih,
                                                        const float* __restrict__ bhh,
                                                        const float* __restrict__ cout,
                                                        float* __restrict__ hl,
                                                        float* __restrict__ cl, int N) {
    int t = threadIdx.x, nb = blockIdx.x * 8;
    __shared__ __align__(16) float hlL[8][64];
    __shared__ float gL[8][256];
    for (int idx = t; idx < 512; idx += 256) {
        int n = idx >> 6, k = idx & 63;
        hlL[n][k] = hl[(nb + n) * 64 + k];
    }
    __syncthreads();
    {
        float acc[8];
#pragma unroll
        for (int n = 0; n < 8; n++) acc[n] = 0.f;
        const float4* w4p = (const float4*)(wc + t * 64);
#pragma unroll 4
        for (int k4 = 0; k4 < 16; k4++) {
            float4 w4 = w4p[k4];
#pragma unroll
            for (int n = 0; n < 8; n++) acc[n] += dot4(w4, *(const float4*)&hlL[n][k4 * 4]);
        }
        float bs = bih[t] + bhh[t];
#pragma unroll
        for (int n = 0; n < 8; n++) gL[n][t] = acc[n] + cout[(size_t)(nb + n) * 256 + t] + bs;
    }
    __syncthreads();
    for (int idx = t; idx < 512; idx += 256) {
        int n = idx >> 6, k = idx & 63;
        int node = nb + n;
        float gi = gL[n][k], gf = gL[n][64 + k], gg = gL[n][128 + k], go = gL[n][192 + k];
        float c = sigmoidf_(gf) * cl[node * 64 + k] + sigmoidf_(gi) * tanhf(gg);
        cl[node * 64 + k] = c;
        hl[node * 64 + k] = sigmoidf_(go) * tanhf(c);
    }
}

// ---------------- head: persistent blocks, LDS-staged bf16 W1 ----------------
__global__ __launch_bounds__(256) void head_kernel(
    const float* __restrict__ h, const float* __restrict__ hl, const int* __restrict__ ti,
    const int* __restrict__ tc, const float* __restrict__ w1, const float* __restrict__ b1,
    const float* __restrict__ g1, const float* __restrict__ bn1, const float* __restrict__ w2,
    const float* __restrict__ b2, float* __restrict__ out, int P) {
    __shared__ uint2 w1q[6144];
    __shared__ float catL[4][384];
    int t = threadIdx.x;
    const float4* w1f4 = (const float4*)w1;
#pragma unroll
    for (int i = 0; i < 24; i++) {
        int f = t + i * 256;
        float4 v = w1f4[f];
        int j = f / 96, k4 = f - j * 96;
        w1q[k4 * 64 + j] = make_uint2(pack2bf(v.x, v.y), pack2bf(v.z, v.w));
    }
    int j = t & 63, pl = t >> 6;
    float b1j = b1[j], g1j = g1[j], bnj = bn1[j];
    __syncthreads();

    for (int pb = blockIdx.x * 4; pb < P; pb += gridDim.x * 4) {
#pragma unroll
        for (int i = 0; i < 6; i++) {
            int idx = t + i * 256;
            int p = idx / 384, kk = idx - p * 384;
            int pair = pb + p;
            if (pair >= P) pair = P - 1;
            int a0 = ti[pair], a1 = ti[P + pair];
            int s = kk >> 6, k = kk & 63;
            float v;
            if (s == 0 || s == 3) v = h[a0 * 64 + k];
            else if (s == 1 || s == 5) v = h[a1 * 64 + k];
            else if (s == 2) v = hl[a0 * 64 + k];
            else v = hl[a1 * 64 + k];
            catL[p][kk] = v;
        }
        __syncthreads();
        int pair = pb + pl;
        float acc = b1j;
#pragma unroll 8
        for (int k4 = 0; k4 < 96; k4++) {
            uint2 wv = w1q[k4 * 64 + j];
            float4 c = *(const float4*)&catL[pl][k4 * 4];
            acc += __uint_as_float(wv.x << 16) * c.x + __uint_as_float(wv.x & 0xffff0000u) * c.y;
            acc += __uint_as_float(wv.y << 16) * c.z + __uint_as_float(wv.y & 0xffff0000u) * c.w;
        }
        float s1 = acc, s2v = acc * acc;
#pragma unroll
        for (int m = 32; m >= 1; m >>= 1) { s1 += __shfl_xor(s1, m); s2v += __shfl_xor(s2v, m); }
        float mu = s1 * (1.0f / 64.0f);
        float var = fmaxf(s2v * (1.0f / 64.0f) - mu * mu, 0.0f);
        float p1 = fmaxf((acc - mu) * rsqrtf(var + EPS_LN) * g1j + bnj, 0.0f);
        int cls = tc[pair < P ? pair : P - 1];
        float part = p1 * w2[cls * 64 + j];
#pragma unroll
        for (int m = 32; m >= 1; m >>= 1) part += __shfl_xor(part, m);
        if (j == 0 && pair < P) out[pair] = part + b2[cls];
        __syncthreads();
    }
}

extern "C" void kernel_launch(void* const* d_in, const int* in_sizes, int n_in,
                              void* d_out, int out_size, void* d_ws, size_t ws_size,
                              hipStream_t stream) {
    const float* x = (const float*)d_in[0];
    const float* edge_attr = (const float*)d_in[1];
    const float* lin0_w = (const float*)d_in[2];
    const float* lin0_b = (const float*)d_in[3];
    const float* enn_w1 = (const float*)d_in[4];
    const float* enn_b1 = (const float*)d_in[5];
    const float* enn_g1 = (const float*)d_in[6];
    const float* enn_b1n = (const float*)d_in[7];
    const float* enn_w2 = (const float*)d_in[8];
    const float* enn_b2 = (const float*)d_in[9];
    const float* enn_g2 = (const float*)d_in[10];
    const float* enn_b2n = (const float*)d_in[11];
    const float* conv_bias = (const float*)d_in[12];
    const float* gru_w_ih = (const float*)d_in[13];
    const float* gru_w_hh = (const float*)d_in[14];
    const float* gru_b_ih = (const float*)d_in[15];
    const float* gru_b_hh = (const float*)d_in[16];
    const float* lstm_w_ih = (const float*)d_in[17];
    const float* lstm_w_hh = (const float*)d_in[18];
    const float* lstm_b_ih = (const float*)d_in[19];
    const float* lstm_b_hh = (const float*)d_in[20];
    const float* lin1_w = (const float*)d_in[21];
    const float* lin1_b = (const float*)d_in[22];
    const float* lin1_g = (const float*)d_in[23];
    const float* lin1_bn = (const float*)d_in[24];
    const float* lin2_w = (const float*)d_in[25];
    const float* lin2_b = (const float*)d_in[26];
    const int* edge_index = (const int*)d_in[27];
    const int* target_index = (const int*)d_in[28];
    const int* target_class = (const int*)d_in[29];

    const int N = in_sizes[0] / 16;
    const int E = in_sizes[27] / 2;
    const int P = in_sizes[29];

    size_t off = 0;
    auto carve = [&](size_t bytes) {
        void* p = (char*)d_ws + off;
        off += (bytes + 255) & ~(size_t)255;
        return p;
    };
    unsigned short* zbuf = (unsigned short*)carve((size_t)E * 4096 * 2);  // ew bf16 [e][o*64+d]
    unsigned short* e1h = (unsigned short*)carve((size_t)E * 128 * 2);    // pre-swizzled
    unsigned short* e1l = (unsigned short*)carve((size_t)E * 128 * 2);    // pre-swizzled
    unsigned short* w2gp = (unsigned short*)carve((size_t)4096 * 128 * 2);  // chunk-permuted+swz
    float* b2g = (float*)carve((size_t)4096 * 4);
    float* hbuf = (float*)carve((size_t)N * 64 * 4);
    float* counts = (float*)carve((size_t)N * 4 + (size_t)3 * N * 64 * 4);
    float* agg0 = counts + N;
    float* agg1 = agg0 + (size_t)N * 64;
    float* agg2 = agg1 + (size_t)N * 64;
    float* hl = (float*)carve((size_t)N * 64 * 4);
    float* cl = (float*)carve((size_t)N * 64 * 4);
    float* cout_b = (float*)carve((size_t)N * 256 * 4);
    float* wc = (float*)carve((size_t)256 * 64 * 4);
    float* stats = (float*)carve((size_t)E * 2 * 4);
    unsigned short* mb = (unsigned short*)carve((size_t)128 * 128 * 2);
    float* varr = (float*)carve((size_t)128 * 4);
    float* cw = (float*)carve((size_t)128 * 4);
    float* sbc = (float*)carve((size_t)2 * 4);
    float* pv = (float*)carve((size_t)256 * 128 * 4);
    float* pcw = (float*)carve((size_t)256 * 128 * 4);
    float* psb = (float*)carve((size_t)256 * 4);
    float* pc = (float*)carve((size_t)256 * 4);
    float* pMT = (float*)carve((size_t)256 * 128 * 128 * 4);
    (void)ws_size;

    hipMemsetAsync(counts, 0, (size_t)N * 4 + (size_t)3 * N * 64 * 4, stream);
    init_kernel<<<(N * 64 + 255) / 256, 256, 0, stream>>>(x, lin0_w, lin0_b, hbuf, edge_index,
                                                          counts, N, E);
    edge_nn1_kernel<<<E, 128, 0, stream>>>(edge_attr, enn_w1, enn_b1, enn_g1, enn_b1n, e1h, e1l, E);
    mpart_kernel<<<256, 128, 0, stream>>>(enn_w2, enn_b2, enn_g2, w2gp, b2g, pMT, pv, pcw, psb, pc);
    mreduce_kernel<<<64, 256, 0, stream>>>(pMT, pv, pcw, psb, pc, mb, varr, cw, sbc);
    stats_kernel<<<(E + 63) / 64, 256, 0, stream>>>(e1h, e1l, mb, cw, varr, sbc, stats, E);
    {
        int NT = (E + 63) / 64;
        dim3 g(32, (NT + ZTILES - 1) / ZTILES);
        zgemm_final<<<g, 256, 0, stream>>>(e1h, w2gp, b2g, enn_g2, enn_b2n, stats, zbuf, E);
    }

    float* aggs[3] = {agg0, agg1, agg2};
    for (int it = 0; it < 3; it++) {
        msg_kernel<<<E / 4, 256, 0, stream>>>(zbuf, hbuf, edge_index, aggs[it], E);
        gru_kernel<<<N / 8, 192, 0, stream>>>(aggs[it], counts, conv_bias, gru_w_ih, gru_w_hh,
                                              gru_b_ih, gru_b_hh, hbuf, N);
    }

    coutprep_kernel<<<N / 8, 256, 0, stream>>>(hbuf, lstm_w_ih, lstm_w_hh, lstm_b_ih, lstm_b_hh,
                                               cout_b, wc, hl, cl, N);
    lstm_step_kernel<<<N / 8, 256, 0, stream>>>(wc, lstm_b_ih, lstm_b_hh, cout_b, hl, cl, N);
    lstm_step_kernel<<<N / 8, 256, 0, stream>>>(wc, lstm_b_ih, lstm_b_hh, cout_b, hl, cl, N);

    head_kernel<<<512, 256, 0, stream>>>(hbuf, hl, target_index, target_class, lin1_w, lin1_b,
                                         lin1_g, lin1_bn, lin2_w, lin2_b, (float*)d_out, P);
}